// Round 11
// baseline (292.984 us; speedup 1.0000x reference)
//
#include <hip/hip_runtime.h>

typedef __attribute__((ext_vector_type(8))) short short8;
typedef __attribute__((ext_vector_type(8))) unsigned short us8;
typedef __attribute__((ext_vector_type(4))) unsigned short us4;
typedef __attribute__((ext_vector_type(4))) float f32x4;

__device__ __forceinline__ float bf2f(unsigned short h) {
  return __uint_as_float(((unsigned int)h) << 16);
}
__device__ __forceinline__ unsigned short f2bf(float f) {
  unsigned int u = __float_as_uint(f);
  u += 0x7FFF + ((u >> 16) & 1);
  return (unsigned short)(u >> 16);
}

// async global->LDS, 16B per lane. LDS dest is wave-uniform base; HW adds lane*16.
__device__ __forceinline__ void gload16(const void* g, void* l) {
  __builtin_amdgcn_global_load_lds(
      (const __attribute__((address_space(1))) unsigned int*)g,
      (__attribute__((address_space(3))) unsigned int*)l, 16, 0, 0);
}

#define BM 128
#define BN 128
#define BK 32

struct EpiParams {
  const float* bias;   // [out cols] or null
  const float* aux0;   // EPI2: query_xyz ; EPI0: query_feat (residual)
  const float* aux1;   // EPI2: key_xyz  ; EPI4: bvo (folded V-bias)
  const void*  aux2;   // EPI2/EPI0: lsum ; EPI4: VWT dest
  long  saux;          // xyz batch stride (elements)
  float scale;         // EPI2: 1/sqrt(D)
};

// ---------- small-tile GEMM (projections / Wvo), proven structure ----------
template<int EPI>
__global__ __launch_bounds__(256)
void gemm_bt(const unsigned short* __restrict__ A, const unsigned short* __restrict__ B,
             void* __restrict__ Cout, int Kd, int lda, int ldb, int ldc,
             long sA, long sB, long sC, EpiParams ep)
{
  __shared__ __attribute__((aligned(16))) char smem[16384];
  char* Al = smem;
  char* Bl = smem + 8192;

  const int t    = threadIdx.x;
  const int lane = t & 63;
  const int wid  = t >> 6;
  const int wr   = wid >> 1;
  const int wc   = wid & 1;
  const int tr   = lane & 15;
  const int tg   = lane >> 4;

  const int bz    = blockIdx.z;
  const int rbase = blockIdx.y * BM;
  const int cbase = blockIdx.x * BN;

  const unsigned short* Ab = A + (long)bz * sA;
  const unsigned short* Bb = B + (long)bz * sB;
  const char* Asrc = (const char*)(Ab + (long)rbase * lda);
  const char* Bsrc = (const char*)(Bb + (long)cbase * ldb);
  const long lda_b = (long)lda * 2;
  const long ldb_b = (long)ldb * 2;

  f32x4 acc[4][4] = {};

  for (int k0 = 0; k0 < Kd; k0 += BK) {
#pragma unroll
    for (int it = 0; it < 2; ++it) {
      const int boff = (it * 4 + wid) * 1024 + lane * 16;
      const int r  = boff >> 6;
      const int cb = boff & 63;
      gload16(Asrc + (long)r * lda_b + (k0 * 2 + cb), Al + (it * 4 + wid) * 1024);
      gload16(Bsrc + (long)r * ldb_b + (k0 * 2 + cb), Bl + (it * 4 + wid) * 1024);
    }
    __syncthreads();

    short8 af[4], bf[4];
#pragma unroll
    for (int m = 0; m < 4; ++m)
      af[m] = *(const short8*)(Al + ((wr * 64 + m * 16 + tr) * 32 + tg * 8) * 2);
#pragma unroll
    for (int n = 0; n < 4; ++n)
      bf[n] = *(const short8*)(Bl + ((wc * 64 + n * 16 + tr) * 32 + tg * 8) * 2);
#pragma unroll
    for (int m = 0; m < 4; ++m)
#pragma unroll
      for (int n = 0; n < 4; ++n)
        acc[m][n] = __builtin_amdgcn_mfma_f32_16x16x32_bf16(af[m], bf[n], acc[m][n], 0, 0, 0);
    __syncthreads();
  }

  if (EPI == 0) {  // bf16 out (+optional bias): Q projection / Wvo
    unsigned short* C = (unsigned short*)Cout + (long)bz * sC;
#pragma unroll
    for (int n = 0; n < 4; ++n) {
      const int col = cbase + wc * 64 + n * 16 + tr;
      const float bv = ep.bias ? ep.bias[col] : 0.f;
#pragma unroll
      for (int m = 0; m < 4; ++m) {
#pragma unroll
        for (int i = 0; i < 4; ++i) {
          const int row = rbase + wr * 64 + m * 16 + tg * 4 + i;
          C[(long)row * ldc + col] = f2bf(acc[m][n][i] + bv);
        }
      }
    }
  } else {  // EPI 4: combined K|VW projection: cols<512 -> K, else -> VW^T
    if (cbase < 512) {
      unsigned short* C = (unsigned short*)Cout;  // KB
#pragma unroll
      for (int n = 0; n < 4; ++n) {
        const int col = cbase + wc * 64 + n * 16 + tr;
        const float bv = ep.bias[col];
#pragma unroll
        for (int m = 0; m < 4; ++m) {
#pragma unroll
          for (int i = 0; i < 4; ++i) {
            const int row = rbase + wr * 64 + m * 16 + tg * 4 + i;
            C[(long)row * 512 + col] = f2bf(acc[m][n][i] + bv);
          }
        }
      }
    } else {
      unsigned short* C = (unsigned short*)ep.aux2;  // VWT[b][f][m]
#pragma unroll
      for (int n = 0; n < 4; ++n) {
        const int e  = cbase - 512 + wc * 64 + n * 16 + tr;
        const float bv = ep.aux1[e];
#pragma unroll
        for (int m = 0; m < 4; ++m) {
          const int row0 = rbase + wr * 64 + m * 16 + tg * 4;
          const int b  = row0 >> 11;
          const int ml = row0 & 2047;
          us4 v;
#pragma unroll
          for (int i = 0; i < 4; ++i) v[i] = f2bf(acc[m][n][i] + bv);
          *(us4*)(C + ((long)b * 512 + e) * 2048 + ml) = v;
        }
      }
    }
  }
}

// ---------- 256x256 8-phase GEMM (m201-template port), BK=64, 512 thr, 8 waves ----
// Wave grid 2M x 4N; per-wave C = 128x64 = acc[8][4]. LDS: 2 slots x 64KB; slot:
// A-half0 @0, A-half1 @16K, B-half0 @32K, B-half1 @48K (half = 128 rows x 64 K).
// XOR swizzle (verified 0-conflict): granule g of row r holds source granule g^(r&7).
// Phases per 2-K-tile iter: P0..P3 tile t (slot0), P4..P7 tile t+1 (slot1).
// Quadrants: P0(m0,n0) P1(m0,n1) P2(m1,n1) P3(m1,n0); 16 MFMA each.
// Stage 1 half/phase: P0:A1(t+1) P1:B1(t+1) P2:B0(t+2) P3:A0(t+2) P4:A1(t+2)
// P5:B1(t+2) P6:B0(t+3) P7:A0(t+3). Counted vmcnt(4) at END of P3/P7 (pre-barrier)
// so every wave certifies its own loads before any wave's next ds_read.
// EPI 0: PV-fold fp32 out = acc/l + bo + residual. EPI 2: scores P=exp(..)+row sums.
template<int EPI>
__global__ __launch_bounds__(512, 1)
void gemm8p(const unsigned short* __restrict__ A, const unsigned short* __restrict__ B,
            void* __restrict__ Cout, int Kd, int lda, int ldb, int ldc,
            long sA, long sB, long sC, int ntn, EpiParams ep)
{
  __shared__ __attribute__((aligned(16))) char smem[137216];

  const int t    = threadIdx.x;
  const int lane = t & 63;
  const int wid  = t >> 6;     // 0..7
  const int wr   = wid >> 2;   // 0..1  M-half
  const int wc   = wid & 3;    // 0..3  N-quarter
  const int tr   = lane & 15;
  const int tg   = lane >> 4;

  const int bz    = blockIdx.x;                  // batch -> XCD
  const int rbase = (blockIdx.y / ntn) * 256;
  const int cbase = (blockIdx.y % ntn) * 256;

  const long lda_b = (long)lda * 2;
  const long ldb_b = (long)ldb * 2;
  const char* Asrc = (const char*)(A + (long)bz * sA + (long)rbase * lda);
  const char* Bsrc = (const char*)(B + (long)bz * sB + (long)cbase * ldb);

  const int srow = t >> 3;                    // 0..63
  const int sg   = (t & 7) ^ ((t >> 3) & 7);  // pre-swizzled source granule

  if (EPI == 2) {  // xyz staging (region above the 128 KB slots)
    float* qs  = (float*)(smem + 131072);
    float* ks2 = (float*)(smem + 131072 + 3072);
    if (t < 256) {
      const float* q = ep.aux0 + (long)bz * ep.saux + (long)(rbase + t) * 3;
      qs[t * 3] = q[0]; qs[t * 3 + 1] = q[1]; qs[t * 3 + 2] = q[2];
    } else {
      const int tt = t - 256;
      const float* k2 = ep.aux1 + (long)bz * ep.saux + (long)(cbase + tt) * 3;
      ks2[tt * 3] = k2[0]; ks2[tt * 3 + 1] = k2[1]; ks2[tt * 3 + 2] = k2[2];
    }
  }

// stage half-tile: mat 0=A/1=B, half h, K-tile tk, slot byte base sb. 2 gloads/thread.
#define STAGEH(mat, h, tk, sb) {                                              \
    char* _d = smem + (sb) + (mat) * 32768 + (h) * 16384 + wid * 1024;        \
    const long _ldx = (mat) ? ldb_b : lda_b;                                  \
    const char* _s = ((mat) ? Bsrc : Asrc) + (long)((h) * 128 + srow) * _ldx  \
                     + (long)(tk) * 128 + sg * 16;                            \
    gload16(_s, _d);                                                          \
    gload16(_s + 64 * _ldx, _d + 8192); }

#define RDA(sb, mh)                                                           \
    _Pragma("unroll") for (int mm = 0; mm < 4; ++mm) {                        \
      const int lr = (mh) * 64 + mm * 16 + tr;                                \
      _Pragma("unroll") for (int ks = 0; ks < 2; ++ks)                        \
        af[mm][ks] = *(const short8*)(smem + (sb) + Ab0 + lr * 128 +          \
                       (((ks * 4 + tg) ^ (lr & 7)) << 4)); }

#define RDB(sb, nh)                                                           \
    _Pragma("unroll") for (int nn = 0; nn < 2; ++nn) {                        \
      const int lbr = lbr0 + ((nh) * 2 + nn) * 16 + tr;                       \
      _Pragma("unroll") for (int ks = 0; ks < 2; ++ks)                        \
        bf[(nh) * 2 + nn][ks] = *(const short8*)(smem + (sb) + 32768 + Bh0 +  \
                       lbr * 128 + (((ks * 4 + tg) ^ (lbr & 7)) << 4)); }

#define MFQ(mh, nh)                                                           \
    __builtin_amdgcn_s_setprio(1);                                            \
    _Pragma("unroll") for (int mm = 0; mm < 4; ++mm)                          \
    _Pragma("unroll") for (int nn = 0; nn < 2; ++nn)                          \
    _Pragma("unroll") for (int ks = 0; ks < 2; ++ks)                          \
      acc[(mh) * 4 + mm][(nh) * 2 + nn] = __builtin_amdgcn_mfma_f32_16x16x32_bf16( \
          af[mm][ks], bf[(nh) * 2 + nn][ks], acc[(mh) * 4 + mm][(nh) * 2 + nn], 0, 0, 0); \
    __builtin_amdgcn_s_setprio(0);

#define BAR   __builtin_amdgcn_s_barrier()
#define LGKM0 asm volatile("s_waitcnt lgkmcnt(0)" ::: "memory")

  const int Ab0  = wr * 16384;        // wave's A-half
  const int Bh0  = (wc >> 1) * 16384; // wave's B-half
  const int lbr0 = (wc & 1) * 64;

  f32x4 acc[8][4] = {};
  short8 af[4][2], bf[4][2];
  const int NT = Kd >> 6;

  // prologue: tile0 fully, then tile1's B0,A0 (order matters for FIFO vmcnt)
  STAGEH(1, 0, 0, 0) STAGEH(0, 0, 0, 0) STAGEH(0, 1, 0, 0) STAGEH(1, 1, 0, 0)
  STAGEH(1, 0, 1, 65536) STAGEH(0, 0, 1, 65536)
  asm volatile("s_waitcnt vmcnt(4)" ::: "memory");   // tile0 landed; tile1 B0,A0 in flight
  BAR;

#pragma unroll 1
  for (int i2 = 0; i2 < NT; i2 += 2) {
    const bool more = (i2 + 2 < NT);
    // ---- tile i2 (slot 0) ----
    // P0
    RDA(0, 0) RDB(0, 0)
    STAGEH(0, 1, i2 + 1, 65536)
    BAR; LGKM0; MFQ(0, 0) BAR;
    // P1
    RDB(0, 1)
    STAGEH(1, 1, i2 + 1, 65536)
    BAR; LGKM0; MFQ(0, 1) BAR;
    // P2
    RDA(0, 1)
    if (more) STAGEH(1, 0, i2 + 2, 0)
    BAR; LGKM0; MFQ(1, 1) BAR;
    // P3
    if (more) STAGEH(0, 0, i2 + 2, 0)
    BAR; LGKM0; MFQ(1, 0)
    if (more) { asm volatile("s_waitcnt vmcnt(4)" ::: "memory"); }
    else      { asm volatile("s_waitcnt vmcnt(0)" ::: "memory"); }
    BAR;
    // ---- tile i2+1 (slot 1) ----
    // P4
    RDA(65536, 0) RDB(65536, 0)
    if (more) STAGEH(0, 1, i2 + 2, 0)
    BAR; LGKM0; MFQ(0, 0) BAR;
    // P5
    RDB(65536, 1)
    if (more) STAGEH(1, 1, i2 + 2, 0)
    BAR; LGKM0; MFQ(0, 1) BAR;
    // P6
    RDA(65536, 1)
    if (more) STAGEH(1, 0, i2 + 3, 65536)
    BAR; LGKM0; MFQ(1, 1) BAR;
    // P7
    if (more) STAGEH(0, 0, i2 + 3, 65536)
    BAR; LGKM0; MFQ(1, 0)
    if (more) { asm volatile("s_waitcnt vmcnt(4)" ::: "memory"); }
    BAR;
  }
#undef STAGEH
#undef RDA
#undef RDB
#undef MFQ

  if (EPI == 0) {  // PV-fold: fp32 out = acc/l + bo + residual(query_feat)
    float* C = (float*)Cout + (long)bz * sC;
    const float* ls = (const float*)ep.aux2 + (long)bz * 2048 + rbase + wr * 128;
    const float* qf = ep.aux0;
#pragma unroll
    for (int m = 0; m < 8; ++m) {
      const f32x4 lv = *(const f32x4*)(ls + m * 16 + tg * 4);
      f32x4 inv;
#pragma unroll
      for (int i = 0; i < 4; ++i) inv[i] = 1.f / lv[i];
#pragma unroll
      for (int n = 0; n < 4; ++n) {
        const int col = cbase + wc * 64 + n * 16 + tr;
        const float bb = ep.bias[col];
#pragma unroll
        for (int i = 0; i < 4; ++i) {
          const int row = rbase + wr * 128 + m * 16 + tg * 4 + i;
          C[(long)row * ldc + col] =
              acc[m][n][i] * inv[i] + bb + qf[((long)bz * 2048 + row) * 512 + col];
        }
      }
    }
  } else {  // EPI 2: P = exp(s*scale + distbias - 5) + per-row sum atomics
    const float* qs  = (const float*)(smem + 131072);
    const float* ks2 = (const float*)(smem + 131072 + 3072);
    unsigned short* C = (unsigned short*)Cout + (long)bz * sC;
    float* lrow = (float*)ep.aux2 + (long)bz * 2048 + rbase;
    float ps[8][4];
#pragma unroll
    for (int m = 0; m < 8; ++m) {
#pragma unroll
      for (int i = 0; i < 4; ++i) {
        ps[m][i] = 0.f;
        const int rl = wr * 128 + m * 16 + tg * 4 + i;
        const float qx = qs[rl * 3], qy = qs[rl * 3 + 1], qz = qs[rl * 3 + 2];
#pragma unroll
        for (int n = 0; n < 4; ++n) {
          const int cl = wc * 64 + n * 16 + tr;
          const float dx = qx - ks2[cl * 3];
          const float dy = qy - ks2[cl * 3 + 1];
          const float dz = qz - ks2[cl * 3 + 2];
          const float d2 = dx * dx + dy * dy + dz * dz;
          const float d  = sqrtf(fmaxf(d2, 1e-12f));
          const float bias = fmaxf(-2.f * d, -18.420680743952367f);
          const float p = __expf(acc[m][n][i] * ep.scale + bias - 5.f);
          ps[m][i] += p;
          C[(long)(rbase + rl) * ldc + (cbase + cl)] = f2bf(p);
        }
      }
    }
#pragma unroll
    for (int off = 1; off <= 8; off <<= 1)
#pragma unroll
      for (int m = 0; m < 8; ++m)
#pragma unroll
        for (int i = 0; i < 4; ++i)
          ps[m][i] += __shfl_xor(ps[m][i], off, 64);
    if (tr == 0) {
#pragma unroll
      for (int m = 0; m < 8; ++m)
#pragma unroll
        for (int i = 0; i < 4; ++i)
          atomicAdd(&lrow[wr * 128 + m * 16 + tg * 4 + i], ps[m][i]);
    }
  }
}

// LayerNorm rows of 512 fp32; one wave per row
__global__ __launch_bounds__(256)
void ln_rows(const float* __restrict__ X, const float* __restrict__ g,
             const float* __restrict__ b, float* __restrict__ O)
{
  const int row  = blockIdx.x * 4 + (threadIdx.x >> 6);
  const int lane = threadIdx.x & 63;
  const float* xp = X + (long)row * 512;

  f32x4 v0 = *(const f32x4*)(xp + lane * 4);
  f32x4 v1 = *(const f32x4*)(xp + 256 + lane * 4);

  float s = 0.f;
#pragma unroll
  for (int j = 0; j < 4; ++j) s += v0[j] + v1[j];
#pragma unroll
  for (int off = 32; off; off >>= 1) s += __shfl_xor(s, off, 64);
  const float mu = s * (1.f / 512.f);

  float vs = 0.f;
#pragma unroll
  for (int j = 0; j < 4; ++j) {
    float d0 = v0[j] - mu, d1 = v1[j] - mu;
    vs += d0 * d0 + d1 * d1;
  }
#pragma unroll
  for (int off = 32; off; off >>= 1) vs += __shfl_xor(vs, off, 64);
  const float r = rsqrtf(vs * (1.f / 512.f) + 1e-5f);

  f32x4 g0 = *(const f32x4*)(g + lane * 4);
  f32x4 g1 = *(const f32x4*)(g + 256 + lane * 4);
  f32x4 b0 = *(const f32x4*)(b + lane * 4);
  f32x4 b1 = *(const f32x4*)(b + 256 + lane * 4);

  f32x4 o0, o1;
#pragma unroll
  for (int j = 0; j < 4; ++j) {
    o0[j] = (v0[j] - mu) * r * g0[j] + b0[j];
    o1[j] = (v1[j] - mu) * r * g1[j] + b1[j];
  }
  float* op = O + (long)row * 512;
  *(f32x4*)(op + lane * 4) = o0;
  *(f32x4*)(op + 256 + lane * 4) = o1;
}

// fp32 -> bf16 for the two feature tensors (blockIdx.y selects)
__global__ __launch_bounds__(256)
void cvt_feat(const float* __restrict__ a, const float* __restrict__ b,
              unsigned short* __restrict__ oa, unsigned short* __restrict__ ob)
{
  const float* src = blockIdx.y ? b : a;
  unsigned short* dst = blockIdx.y ? ob : oa;
  const long i = blockIdx.x * 256 + threadIdx.x;
  const f32x4* s = (const f32x4*)src;
  f32x4 x = s[i * 2];
  f32x4 y = s[i * 2 + 1];
  us8 o;
#pragma unroll
  for (int j = 0; j < 4; ++j) { o[j] = f2bf(x[j]); o[4 + j] = f2bf(y[j]); }
  *(us8*)(dst + i * 8) = o;
}

// fp32 -> bf16 for the four weight matrices into one contiguous dst
__global__ __launch_bounds__(256)
void cvt_w(const float* __restrict__ w0, const float* __restrict__ w1,
           const float* __restrict__ w2, const float* __restrict__ w3,
           unsigned short* __restrict__ dst)
{
  const float* src = blockIdx.y == 0 ? w0 : blockIdx.y == 1 ? w1 : blockIdx.y == 2 ? w2 : w3;
  unsigned short* d = dst + (long)blockIdx.y * 262144;
  const long i = blockIdx.x * 256 + threadIdx.x;
  const f32x4* s = (const f32x4*)src;
  f32x4 x = s[i * 2];
  f32x4 y = s[i * 2 + 1];
  us8 o;
#pragma unroll
  for (int j = 0; j < 4; ++j) { o[j] = f2bf(x[j]); o[4 + j] = f2bf(y[j]); }
  *(us8*)(d + i * 8) = o;
}

// transpose+cvt: WvT[d][e] = Wv[e][d], fp32 -> bf16. grid (8,8), 256 thr.
__global__ __launch_bounds__(256)
void cvt_wT(const float* __restrict__ Wv, unsigned short* __restrict__ WvT)
{
  __shared__ float tile[64 * 68];
  const int t = threadIdx.x;
  const int e0 = blockIdx.y * 64, d0 = blockIdx.x * 64;
#pragma unroll
  for (int c = 0; c < 4; ++c) {
    const int L = c * 256 + t;
    const int r = L >> 4, g = L & 15;
    const f32x4 v = *(const f32x4*)(Wv + (long)(e0 + r) * 512 + d0 + g * 4);
    *(f32x4*)(tile + r * 68 + g * 4) = v;
  }
  __syncthreads();
#pragma unroll
  for (int c = 0; c < 2; ++c) {
    const int L = c * 256 + t;
    const int d = L >> 3, ge = L & 7;
    us8 o;
#pragma unroll
    for (int j = 0; j < 8; ++j) o[j] = f2bf(tile[(ge * 8 + j) * 68 + d]);
    *(us8*)(WvT + (long)(d0 + d) * 512 + e0 + ge * 8) = o;
  }
}

// bvo[f] = sum_e Wo[f][e] * bv[e]. grid (2), 256 thr.
__global__ __launch_bounds__(256)
void bvo_k(const float* __restrict__ Wo, const float* __restrict__ bv,
           float* __restrict__ out)
{
  const int f = blockIdx.x * 256 + threadIdx.x;
  float s = 0.f;
  for (int e = 0; e < 512; e += 4) {
    const f32x4 w = *(const f32x4*)(Wo + (long)f * 512 + e);
    const f32x4 b = *(const f32x4*)(bv + e);
    s += w[0] * b[0] + w[1] * b[1] + w[2] * b[2] + w[3] * b[3];
  }
  out[f] = s;
}

extern "C" void kernel_launch(void* const* d_in, const int* in_sizes, int n_in,
                              void* d_out, int out_size, void* d_ws, size_t ws_size,
                              hipStream_t stream)
{
  const float* qxyz  = (const float*)d_in[0];
  const float* qfeat = (const float*)d_in[1];
  const float* kxyz  = (const float*)d_in[2];
  const float* kfeat = (const float*)d_in[3];
  const float* Wq = (const float*)d_in[4];
  const float* bq = (const float*)d_in[5];
  const float* Wk = (const float*)d_in[6];
  const float* bk = (const float*)d_in[7];
  const float* Wv = (const float*)d_in[8];
  const float* bv = (const float*)d_in[9];
  const float* Wo = (const float*)d_in[10];
  const float* bo = (const float*)d_in[11];
  const float* lng = (const float*)d_in[12];
  const float* lnb = (const float*)d_in[13];

  const long SZ_FEAT = 16777216;            // 8*2048*512*2
  char* ws = (char*)d_ws;
  if (ws_size < (size_t)153092096) return;  // need ~150 MB

  unsigned short* XQ  = (unsigned short*)(ws);
  unsigned short* XK  = (unsigned short*)(ws + SZ_FEAT);
  unsigned short* QB  = (unsigned short*)(ws + 2 * SZ_FEAT);
  unsigned short* KB  = (unsigned short*)(ws + 3 * SZ_FEAT);
  unsigned short* VT  = (unsigned short*)(ws + 4 * SZ_FEAT);   // VW^T [b][f][m]
  unsigned short* WQB = (unsigned short*)(ws + 5 * SZ_FEAT);
  unsigned short* WKB = WQB + 262144;       // contiguous K|Wvo weight block [1024][512]
  unsigned short* WVO = WQB + 524288;       // Wvo = Wo*Wv (bf16)
  unsigned short* WOB = WQB + 786432;
  unsigned short* SB  = (unsigned short*)(ws + 5 * SZ_FEAT + 2097152);
  unsigned short* WVT = SB;                 // Wv^T bf16 (dead before scores writes SB)
  float* BVO  = (float*)((char*)SB + 524288); // bvo (dead before scores)
  float* XRES = (float*)ws;                 // spans ws+0..ws+32MB (XQ+XK dead by PV)
  float* LSUM = (float*)(WOB);              // WOB slot: dead after Wvo GEMM (R9-verified)

  // 1. conversions
  cvt_feat<<<dim3(4096, 2), 256, 0, stream>>>(qfeat, kfeat, XQ, XK);
  cvt_w<<<dim3(128, 4), 256, 0, stream>>>(Wq, Wk, Wv, Wo, WQB);
  cvt_wT<<<dim3(8, 8), 256, 0, stream>>>(Wv, WVT);
  bvo_k<<<dim3(2), 256, 0, stream>>>(Wo, bv, BVO);

  // 2. Wvo = Wo * Wv  (via gemm_bt: sum_e Wo[f][e] * WvT[d][e])
  EpiParams ew{};
  gemm_bt<0><<<dim3(4, 4, 1), 256, 0, stream>>>(WOB, WVT, WVO, 512, 512, 512, 512, 0, 0, 0, ew);

  // 3. projections: Q, then combined K | VW (VW = Xk*Wvo^T + bvo, written transposed)
  EpiParams e0{}; e0.bias = bq;
  gemm_bt<0><<<dim3(4, 128, 1), 256, 0, stream>>>(XQ, WQB, QB, 512, 512, 512, 512, 0, 0, 0, e0);
  EpiParams e1{}; e1.bias = bk; e1.aux1 = BVO; e1.aux2 = VT;
  gemm_bt<4><<<dim3(8, 128, 1), 256, 0, stream>>>(XK, WKB, KB, 512, 512, 512, 512, 0, 0, 0, e1);

  // zero row-sum buffer (WOB region dead after Wvo GEMM; stream-ordered)
  hipMemsetAsync(LSUM, 0, 8 * 2048 * sizeof(float), stream);

  // 4. scores -> P = exp(s-5), row sums via atomics; 256^2 8-phase, 512 blocks
  EpiParams es{}; es.aux0 = qxyz; es.aux1 = kxyz; es.aux2 = LSUM; es.saux = 2048 * 3;
  es.scale = 0.044194173824159216f;  // 1/sqrt(512)
  gemm8p<2><<<dim3(8, 64), 512, 0, stream>>>(QB, KB, SB, 512, 512, 512, 2048,
                                             (long)2048 * 512, (long)2048 * 512,
                                             (long)2048 * 2048, 8, es);

  // 5. x = (P @ VW)/l + bo + qfeat : 256^2 8-phase, 128 blocks (tile-count-bound)
  EpiParams ep{}; ep.aux2 = LSUM; ep.bias = bo; ep.aux0 = qfeat;
  gemm8p<0><<<dim3(8, 16), 512, 0, stream>>>(SB, VT, XRES, 2048, 2048, 2048, 512,
                                             (long)2048 * 2048, (long)512 * 2048,
                                             (long)2048 * 512, 2, ep);

  // 6. LayerNorm -> out
  ln_rows<<<4096, 256, 0, stream>>>(XRES, lng, lnb, (float*)d_out);
}

// Round 12
// 267.925 us; speedup vs baseline: 1.0935x; 1.0935x over previous
//
#include <hip/hip_runtime.h>

typedef __attribute__((ext_vector_type(8))) short short8;
typedef __attribute__((ext_vector_type(8))) unsigned short us8;
typedef __attribute__((ext_vector_type(4))) unsigned short us4;
typedef __attribute__((ext_vector_type(4))) float f32x4;

__device__ __forceinline__ float bf2f(unsigned short h) {
  return __uint_as_float(((unsigned int)h) << 16);
}
__device__ __forceinline__ unsigned short f2bf(float f) {
  unsigned int u = __float_as_uint(f);
  u += 0x7FFF + ((u >> 16) & 1);
  return (unsigned short)(u >> 16);
}

// async global->LDS, 16B per lane. LDS dest is wave-uniform base; HW adds lane*16.
__device__ __forceinline__ void gload16(const void* g, void* l) {
  __builtin_amdgcn_global_load_lds(
      (const __attribute__((address_space(1))) unsigned int*)g,
      (__attribute__((address_space(3))) unsigned int*)l, 16, 0, 0);
}

#define BM 128
#define BN 128
#define BK 32

struct EpiParams {
  const float* bias;   // per-epilogue bias vector
  const float* aux0;   // EPI2: query_xyz
  const float* aux1;   // EPI2: key_xyz ; EPI6: bvo
  const void*  aux2;   // EPI2: LPART  ; EPI6: VT dest
  long  saux;          // xyz batch stride (elements)
  float scale;         // EPI2: 1/sqrt(D)
};

// ---------- small-tile GEMM: only used for Wvo = Wo*Wv (4x4 grid) ----------
__global__ __launch_bounds__(256)
void gemm_bt(const unsigned short* __restrict__ A, const unsigned short* __restrict__ B,
             unsigned short* __restrict__ C, int Kd, int lda, int ldb, int ldc)
{
  __shared__ __attribute__((aligned(16))) char smem[16384];
  char* Al = smem;
  char* Bl = smem + 8192;

  const int t    = threadIdx.x;
  const int lane = t & 63;
  const int wid  = t >> 6;
  const int wr   = wid >> 1;
  const int wc   = wid & 1;
  const int tr   = lane & 15;
  const int tg   = lane >> 4;

  const int rbase = blockIdx.y * BM;
  const int cbase = blockIdx.x * BN;

  const char* Asrc = (const char*)(A + (long)rbase * lda);
  const char* Bsrc = (const char*)(B + (long)cbase * ldb);
  const long lda_b = (long)lda * 2;
  const long ldb_b = (long)ldb * 2;

  f32x4 acc[4][4] = {};

  for (int k0 = 0; k0 < Kd; k0 += BK) {
#pragma unroll
    for (int it = 0; it < 2; ++it) {
      const int boff = (it * 4 + wid) * 1024 + lane * 16;
      const int r  = boff >> 6;
      const int cb = boff & 63;
      gload16(Asrc + (long)r * lda_b + (k0 * 2 + cb), Al + (it * 4 + wid) * 1024);
      gload16(Bsrc + (long)r * ldb_b + (k0 * 2 + cb), Bl + (it * 4 + wid) * 1024);
    }
    __syncthreads();

    short8 af[4], bf[4];
#pragma unroll
    for (int m = 0; m < 4; ++m)
      af[m] = *(const short8*)(Al + ((wr * 64 + m * 16 + tr) * 32 + tg * 8) * 2);
#pragma unroll
    for (int n = 0; n < 4; ++n)
      bf[n] = *(const short8*)(Bl + ((wc * 64 + n * 16 + tr) * 32 + tg * 8) * 2);
#pragma unroll
    for (int m = 0; m < 4; ++m)
#pragma unroll
      for (int n = 0; n < 4; ++n)
        acc[m][n] = __builtin_amdgcn_mfma_f32_16x16x32_bf16(af[m], bf[n], acc[m][n], 0, 0, 0);
    __syncthreads();
  }

#pragma unroll
  for (int n = 0; n < 4; ++n) {
    const int col = cbase + wc * 64 + n * 16 + tr;
#pragma unroll
    for (int m = 0; m < 4; ++m) {
#pragma unroll
      for (int i = 0; i < 4; ++i) {
        const int row = rbase + wr * 64 + m * 16 + tg * 4 + i;
        C[(long)row * ldc + col] = f2bf(acc[m][n][i]);
      }
    }
  }
}

// ---------- big-tile GEMM: 256x128, 1-phase, batch->XCD pinned (R3-measured-best) ----
// NWC=2 -> 256 thr, NF=4; NWC=4 -> 512 thr, NF=2. Wave tile 128 x NF*16; acc[8][NF].
// EPI 1: PV -> raw fp32 store (finalization deferred to ln_rows).
// EPI 2: scores -> P = exp(s*scale + distbias - 5) bf16; deterministic LPART row sums.
// EPI 5: bf16 + bias (Q projection).
// EPI 6: combined K|VW projection: cbase<512 -> K (+bk); else VW^T scatter (+bvo).
template<int EPI, int NWC>
__global__ __launch_bounds__(128 * NWC, 2)
void gemm_big(const unsigned short* __restrict__ A, const unsigned short* __restrict__ B,
              void* __restrict__ Cout, int Kd, int lda, int ldb, int ldc,
              long sA, long sB, long sC, int ntn, EpiParams ep)
{
  constexpr int T  = 128 * NWC;
  constexpr int NF = 128 / (NWC * 16);
  constexpr int RA = 16384 / (T * 16);   // A tile 256x32x2B = 16 KB
  constexpr int RB = 8192 / (T * 16);    // B tile 128x32x2B = 8 KB

  __shared__ __attribute__((aligned(16))) char smem[24576];
  char* Al = smem;
  char* Bl = smem + 16384;

  const int t    = threadIdx.x;
  const int lane = t & 63;
  const int wid  = t >> 6;
  const int wr   = wid / NWC;
  const int wc   = wid % NWC;
  const int tr   = lane & 15;
  const int tg   = lane >> 4;

  const int bz    = blockIdx.x;                   // batch -> XCD (gridDim.x == 8)
  const int rbase = (blockIdx.y / ntn) * 256;
  const int cbase = (blockIdx.y % ntn) * 128;

  const unsigned short* Ab = A + (long)bz * sA;
  const unsigned short* Bb = B + (long)bz * sB;
  const char* Asrc = (const char*)(Ab + (long)rbase * lda);
  const char* Bsrc = (const char*)(Bb + (long)cbase * ldb);
  const long lda_b = (long)lda * 2;
  const long ldb_b = (long)ldb * 2;

  f32x4 acc[8][NF] = {};

  for (int k0 = 0; k0 < Kd; k0 += BK) {
#pragma unroll
    for (int r = 0; r < RA; ++r) {
      const int o = (r * T + t) * 16;
      gload16(Asrc + (long)(o >> 6) * lda_b + (k0 * 2 + (o & 63)),
              Al + (r * T + wid * 64) * 16);
    }
#pragma unroll
    for (int r = 0; r < RB; ++r) {
      const int o = (r * T + t) * 16;
      gload16(Bsrc + (long)(o >> 6) * ldb_b + (k0 * 2 + (o & 63)),
              Bl + (r * T + wid * 64) * 16);
    }
    __syncthreads();

    short8 af[8], bf[NF];
#pragma unroll
    for (int m = 0; m < 8; ++m)
      af[m] = *(const short8*)(Al + ((wr * 128 + m * 16 + tr) * 32 + tg * 8) * 2);
#pragma unroll
    for (int n = 0; n < NF; ++n)
      bf[n] = *(const short8*)(Bl + ((wc * (NF * 16) + n * 16 + tr) * 32 + tg * 8) * 2);
#pragma unroll
    for (int m = 0; m < 8; ++m)
#pragma unroll
      for (int n = 0; n < NF; ++n)
        acc[m][n] = __builtin_amdgcn_mfma_f32_16x16x32_bf16(af[m], bf[n], acc[m][n], 0, 0, 0);
    __syncthreads();
  }

  if (EPI == 1) {  // PV: raw fp32 store of acc (finalize in ln_rows)
    float* C = (float*)Cout + (long)bz * sC;
#pragma unroll
    for (int m = 0; m < 8; ++m) {
#pragma unroll
      for (int n = 0; n < NF; ++n) {
        const int col = cbase + wc * (NF * 16) + n * 16 + tr;
#pragma unroll
        for (int i = 0; i < 4; ++i) {
          const int row = rbase + wr * 128 + m * 16 + tg * 4 + i;
          C[(long)row * ldc + col] = acc[m][n][i];
        }
      }
    }
  } else if (EPI == 5) {  // Q projection: bf16 + bias
    unsigned short* C = (unsigned short*)Cout + (long)bz * sC;
#pragma unroll
    for (int n = 0; n < NF; ++n) {
      const int col = cbase + wc * (NF * 16) + n * 16 + tr;
      const float bb = ep.bias[col];
#pragma unroll
      for (int m = 0; m < 8; ++m) {
#pragma unroll
        for (int i = 0; i < 4; ++i) {
          const int row = rbase + wr * 128 + m * 16 + tg * 4 + i;
          C[(long)row * ldc + col] = f2bf(acc[m][n][i] + bb);
        }
      }
    }
  } else if (EPI == 6) {  // combined K|VW projection
    if (cbase < 512) {
      unsigned short* C = (unsigned short*)Cout + (long)bz * sC;
#pragma unroll
      for (int n = 0; n < NF; ++n) {
        const int col = cbase + wc * (NF * 16) + n * 16 + tr;
        const float bb = ep.bias[col];
#pragma unroll
        for (int m = 0; m < 8; ++m) {
#pragma unroll
          for (int i = 0; i < 4; ++i) {
            const int row = rbase + wr * 128 + m * 16 + tg * 4 + i;
            C[(long)row * 512 + col] = f2bf(acc[m][n][i] + bb);
          }
        }
      }
    } else {
      unsigned short* C = (unsigned short*)ep.aux2;  // VT[b][f][m]
#pragma unroll
      for (int n = 0; n < NF; ++n) {
        const int e  = cbase - 512 + wc * (NF * 16) + n * 16 + tr;
        const float bb = ep.aux1[e];
#pragma unroll
        for (int m = 0; m < 8; ++m) {
          const int row0 = rbase + wr * 128 + m * 16 + tg * 4;  // within batch (<2048)
          us4 v;
#pragma unroll
          for (int i = 0; i < 4; ++i) v[i] = f2bf(acc[m][n][i] + bb);
          *(us4*)(C + ((long)bz * 512 + e) * 2048 + row0) = v;
        }
      }
    }
  } else {  // EPI 2: scores. P = exp(s*scale + distbias - 5); LPART partial sums (NWC==2)
    float* qs = (float*)smem;          // 256*3 floats
    float* ks = (float*)smem + 768;    // 128*3 floats
    {
      const float* q = ep.aux0 + (long)bz * ep.saux + (long)(rbase + t) * 3;
      qs[t * 3] = q[0]; qs[t * 3 + 1] = q[1]; qs[t * 3 + 2] = q[2];
      if (t < 128) {
        const float* k2 = ep.aux1 + (long)bz * ep.saux + (long)(cbase + t) * 3;
        ks[t * 3] = k2[0]; ks[t * 3 + 1] = k2[1]; ks[t * 3 + 2] = k2[2];
      }
    }
    __syncthreads();
    unsigned short* C = (unsigned short*)Cout + (long)bz * sC;
    float ps[8][4];
#pragma unroll
    for (int m = 0; m < 8; ++m) {
#pragma unroll
      for (int i = 0; i < 4; ++i) {
        ps[m][i] = 0.f;
        const int rl = wr * 128 + m * 16 + tg * 4 + i;
        const float qx = qs[rl * 3], qy = qs[rl * 3 + 1], qz = qs[rl * 3 + 2];
#pragma unroll
        for (int n = 0; n < NF; ++n) {
          const int cl = wc * (NF * 16) + n * 16 + tr;
          const float dx = qx - ks[cl * 3];
          const float dy = qy - ks[cl * 3 + 1];
          const float dz = qz - ks[cl * 3 + 2];
          const float d2 = dx * dx + dy * dy + dz * dz;
          const float d  = sqrtf(fmaxf(d2, 1e-12f));
          // log(exp(-2d)+1e-8) ~= max(-2d, ln(1e-8)); shifted exp (no-max softmax)
          const float bias = fmaxf(-2.f * d, -18.420680743952367f);
          const float p = __expf(acc[m][n][i] * ep.scale + bias - 5.f);
          ps[m][i] += p;
          C[(long)(rbase + rl) * ldc + (cbase + cl)] = f2bf(p);
        }
      }
    }
    // reduce over the 16 tr-lanes (cols within wave)
#pragma unroll
    for (int off = 1; off <= 8; off <<= 1)
#pragma unroll
      for (int m = 0; m < 8; ++m)
#pragma unroll
        for (int i = 0; i < 4; ++i)
          ps[m][i] += __shfl_xor(ps[m][i], off, 64);
    // combine the two wc half-sums per row in LDS, then one deterministic store
    float* sPart = (float*)(smem + 8192);   // [2][256], clear of qs/ks (4.6 KB)
    if (tr == 0) {
#pragma unroll
      for (int m = 0; m < 8; ++m)
#pragma unroll
        for (int i = 0; i < 4; ++i)
          sPart[wc * 256 + wr * 128 + m * 16 + tg * 4 + i] = ps[m][i];
    }
    __syncthreads();
    if (t < 256) {
      float* lp = (float*)ep.aux2 +
                  (long)bz * 32768 + (long)(blockIdx.y % ntn) * 2048 + rbase + t;
      *lp = sPart[t] + sPart[256 + t];
    }
  }
}

// LayerNorm + fold finalization: x = XRES/l + bo + qfeat, then LN. One wave per row.
__global__ __launch_bounds__(256)
void ln_rows(const float* __restrict__ X, const float* __restrict__ LPART,
             const float* __restrict__ qf, const float* __restrict__ bo,
             const float* __restrict__ g, const float* __restrict__ b,
             float* __restrict__ O)
{
  const int row  = blockIdx.x * 4 + (threadIdx.x >> 6);
  const int lane = threadIdx.x & 63;
  const int bz   = row >> 11;
  const int rl   = row & 2047;

  // l = sum of 16 column-block partials
  float p = LPART[(long)bz * 32768 + (long)(lane & 15) * 2048 + rl];
#pragma unroll
  for (int off = 1; off <= 8; off <<= 1) p += __shfl_xor(p, off, 64);
  const float inv = 1.f / p;

  const float* xp = X + (long)row * 512;
  const float* qp = qf + (long)row * 512;

  f32x4 x0 = *(const f32x4*)(xp + lane * 4);
  f32x4 x1 = *(const f32x4*)(xp + 256 + lane * 4);
  const f32x4 q0 = *(const f32x4*)(qp + lane * 4);
  const f32x4 q1 = *(const f32x4*)(qp + 256 + lane * 4);
  const f32x4 o0b = *(const f32x4*)(bo + lane * 4);
  const f32x4 o1b = *(const f32x4*)(bo + 256 + lane * 4);

#pragma unroll
  for (int j = 0; j < 4; ++j) {
    x0[j] = x0[j] * inv + o0b[j] + q0[j];
    x1[j] = x1[j] * inv + o1b[j] + q1[j];
  }

  float s = 0.f;
#pragma unroll
  for (int j = 0; j < 4; ++j) s += x0[j] + x1[j];
#pragma unroll
  for (int off = 32; off; off >>= 1) s += __shfl_xor(s, off, 64);
  const float mu = s * (1.f / 512.f);

  float vs = 0.f;
#pragma unroll
  for (int j = 0; j < 4; ++j) {
    float d0 = x0[j] - mu, d1 = x1[j] - mu;
    vs += d0 * d0 + d1 * d1;
  }
#pragma unroll
  for (int off = 32; off; off >>= 1) vs += __shfl_xor(vs, off, 64);
  const float r = rsqrtf(vs * (1.f / 512.f) + 1e-5f);

  const f32x4 g0 = *(const f32x4*)(g + lane * 4);
  const f32x4 g1 = *(const f32x4*)(g + 256 + lane * 4);
  const f32x4 b0 = *(const f32x4*)(b + lane * 4);
  const f32x4 b1 = *(const f32x4*)(b + 256 + lane * 4);

  f32x4 o0, o1;
#pragma unroll
  for (int j = 0; j < 4; ++j) {
    o0[j] = (x0[j] - mu) * r * g0[j] + b0[j];
    o1[j] = (x1[j] - mu) * r * g1[j] + b1[j];
  }
  float* op = O + (long)row * 512;
  *(f32x4*)(op + lane * 4) = o0;
  *(f32x4*)(op + 256 + lane * 4) = o1;
}

// fp32 -> bf16 for the two feature tensors (blockIdx.y selects)
__global__ __launch_bounds__(256)
void cvt_feat(const float* __restrict__ a, const float* __restrict__ b,
              unsigned short* __restrict__ oa, unsigned short* __restrict__ ob)
{
  const float* src = blockIdx.y ? b : a;
  unsigned short* dst = blockIdx.y ? ob : oa;
  const long i = blockIdx.x * 256 + threadIdx.x;
  const f32x4* s = (const f32x4*)src;
  f32x4 x = s[i * 2];
  f32x4 y = s[i * 2 + 1];
  us8 o;
#pragma unroll
  for (int j = 0; j < 4; ++j) { o[j] = f2bf(x[j]); o[4 + j] = f2bf(y[j]); }
  *(us8*)(dst + i * 8) = o;
}

// fp32 -> bf16 for the four weight matrices into one contiguous dst
__global__ __launch_bounds__(256)
void cvt_w(const float* __restrict__ w0, const float* __restrict__ w1,
           const float* __restrict__ w2, const float* __restrict__ w3,
           unsigned short* __restrict__ dst)
{
  const float* src = blockIdx.y == 0 ? w0 : blockIdx.y == 1 ? w1 : blockIdx.y == 2 ? w2 : w3;
  unsigned short* d = dst + (long)blockIdx.y * 262144;
  const long i = blockIdx.x * 256 + threadIdx.x;
  const f32x4* s = (const f32x4*)src;
  f32x4 x = s[i * 2];
  f32x4 y = s[i * 2 + 1];
  us8 o;
#pragma unroll
  for (int j = 0; j < 4; ++j) { o[j] = f2bf(x[j]); o[4 + j] = f2bf(y[j]); }
  *(us8*)(d + i * 8) = o;
}

// transpose+cvt: WvT[d][e] = Wv[e][d], fp32 -> bf16. grid (8,8), 256 thr.
__global__ __launch_bounds__(256)
void cvt_wT(const float* __restrict__ Wv, unsigned short* __restrict__ WvT)
{
  __shared__ float tile[64 * 68];
  const int t = threadIdx.x;
  const int e0 = blockIdx.y * 64, d0 = blockIdx.x * 64;
#pragma unroll
  for (int c = 0; c < 4; ++c) {
    const int L = c * 256 + t;
    const int r = L >> 4, g = L & 15;
    const f32x4 v = *(const f32x4*)(Wv + (long)(e0 + r) * 512 + d0 + g * 4);
    *(f32x4*)(tile + r * 68 + g * 4) = v;
  }
  __syncthreads();
#pragma unroll
  for (int c = 0; c < 2; ++c) {
    const int L = c * 256 + t;
    const int d = L >> 3, ge = L & 7;
    us8 o;
#pragma unroll
    for (int j = 0; j < 8; ++j) o[j] = f2bf(tile[(ge * 8 + j) * 68 + d]);
    *(us8*)(WvT + (long)(d0 + d) * 512 + e0 + ge * 8) = o;
  }
}

// bvo[f] = sum_e Wo[f][e] * bv[e]. grid (2), 256 thr.
__global__ __launch_bounds__(256)
void bvo_k(const float* __restrict__ Wo, const float* __restrict__ bv,
           float* __restrict__ out)
{
  const int f = blockIdx.x * 256 + threadIdx.x;
  float s = 0.f;
  for (int e = 0; e < 512; e += 4) {
    const f32x4 w = *(const f32x4*)(Wo + (long)f * 512 + e);
    const f32x4 b = *(const f32x4*)(bv + e);
    s += w[0] * b[0] + w[1] * b[1] + w[2] * b[2] + w[3] * b[3];
  }
  out[f] = s;
}

extern "C" void kernel_launch(void* const* d_in, const int* in_sizes, int n_in,
                              void* d_out, int out_size, void* d_ws, size_t ws_size,
                              hipStream_t stream)
{
  const float* qxyz  = (const float*)d_in[0];
  const float* qfeat = (const float*)d_in[1];
  const float* kxyz  = (const float*)d_in[2];
  const float* kfeat = (const float*)d_in[3];
  const float* Wq = (const float*)d_in[4];
  const float* bq = (const float*)d_in[5];
  const float* Wk = (const float*)d_in[6];
  const float* bk = (const float*)d_in[7];
  const float* Wv = (const float*)d_in[8];
  const float* bv = (const float*)d_in[9];
  const float* Wo = (const float*)d_in[10];
  const float* bo = (const float*)d_in[11];
  const float* lng = (const float*)d_in[12];
  const float* lnb = (const float*)d_in[13];

  const long SZ_FEAT = 16777216;            // 8*2048*512*2
  char* ws = (char*)d_ws;
  if (ws_size < (size_t)153092096) return;  // need ~150 MB

  unsigned short* XQ  = (unsigned short*)(ws);
  unsigned short* XK  = (unsigned short*)(ws + SZ_FEAT);
  unsigned short* QB  = (unsigned short*)(ws + 2 * SZ_FEAT);
  unsigned short* KB  = (unsigned short*)(ws + 3 * SZ_FEAT);
  unsigned short* VT  = (unsigned short*)(ws + 4 * SZ_FEAT);   // VW^T [b][f][m]
  unsigned short* WQB = (unsigned short*)(ws + 5 * SZ_FEAT);   // 2MB weight block
  unsigned short* WKB = WQB + 262144;       // [Wk|Wvo] contiguous [1024][512]
  unsigned short* WVO = WQB + 524288;
  unsigned short* WOB = WQB + 786432;
  unsigned short* SB  = (unsigned short*)(ws + 5 * SZ_FEAT + 2097152);
  unsigned short* WVT = SB;                 // Wv^T bf16 (dead before scores writes SB)
  float* BVO  = (float*)((char*)SB + 524288); // bvo (dead before scores)
  float* XRES = (float*)ws;                 // spans ws+0..32MB (XQ+XK dead by PV)
  float* LPART = (float*)WQB;               // 2MB: weight block dead after projections;
                                            // outside XRES span (R9 lesson)

  // 1. conversions
  cvt_feat<<<dim3(4096, 2), 256, 0, stream>>>(qfeat, kfeat, XQ, XK);
  cvt_w<<<dim3(128, 4), 256, 0, stream>>>(Wq, Wk, Wv, Wo, WQB);
  cvt_wT<<<dim3(8, 8), 256, 0, stream>>>(Wv, WVT);
  bvo_k<<<dim3(2), 256, 0, stream>>>(Wo, bv, BVO);

  // 2. Wvo = Wo * Wv  (C[f][d] = sum_e Wo[f][e] * WvT[d][e])
  gemm_bt<<<dim3(4, 4), 256, 0, stream>>>(WOB, WVT, WVO, 512, 512, 512, 512);

  // 3. projections (256x128 tiles, batch->XCD):
  //    Q = Xq*Wq^T + bq ; combined [K|VW] = Xk*[Wk|Wvo]^T (+bk | +bvo, VW transposed)
  EpiParams e0{}; e0.bias = bq;
  gemm_big<5, 2><<<dim3(8, 32), 256, 0, stream>>>(XQ, WQB, QB, 512, 512, 512, 512,
                                                  (long)2048 * 512, 0, (long)2048 * 512, 4, e0);
  EpiParams e1{}; e1.bias = bk; e1.aux1 = BVO; e1.aux2 = VT;
  gemm_big<6, 2><<<dim3(8, 64), 256, 0, stream>>>(XK, WKB, KB, 512, 512, 512, 512,
                                                  (long)2048 * 512, 0, (long)2048 * 512, 8, e1);

  // 4. scores -> P = exp(s-5) bf16 + deterministic LPART row sums (weight block now dead)
  EpiParams es{}; es.aux0 = qxyz; es.aux1 = kxyz; es.aux2 = LPART; es.saux = 2048 * 3;
  es.scale = 0.044194173824159216f;  // 1/sqrt(512)
  gemm_big<2, 2><<<dim3(8, 128), 256, 0, stream>>>(QB, KB, SB, 512, 512, 512, 2048,
                                                   (long)2048 * 512, (long)2048 * 512,
                                                   (long)2048 * 2048, 16, es);

  // 5. XRES = P @ VW (raw, unnormalized) : 256x128 tiles NWC=4
  EpiParams ep{};
  gemm_big<1, 4><<<dim3(8, 32), 512, 0, stream>>>(SB, VT, XRES, 2048, 2048, 2048, 512,
                                                  (long)2048 * 2048, (long)512 * 2048,
                                                  (long)2048 * 512, 4, ep);

  // 6. finalize + LayerNorm: x = XRES/l + bo + qfeat -> LN -> out
  ln_rows<<<4096, 256, 0, stream>>>(XRES, LPART, qfeat, bo, lng, lnb, (float*)d_out);
}